// Round 6
// baseline (298.119 us; speedup 1.0000x reference)
//
#include <hip/hip_runtime.h>
#include <stdint.h>
#include <stddef.h>

// ---------------------------------------------------------------------------
// MaskedMultiHeadAttn: B=2, S=2048, D=1024, H=16, DK=64, fp32 in/out.
// scores = K·Q^T (roles swapped), NO 1/sqrt(dk) scale, causal+pad mask.
// R6 = R5 with the ls race fixed: row-sum partials are per-(b,h,s) (were
//     per-(b,s) -> 16 heads raced). Paired causal bands + j-parity split,
//     1024 uniform blocks (4/CU), unnormalized bf16 O-partials + f32 ls
//     partials merged by k_merge. S^T QK + bpermute PV, no P LDS.
// ---------------------------------------------------------------------------

typedef short bf16x8 __attribute__((ext_vector_type(8)));  // 8 bf16 = 4 VGPR
typedef float f32x4  __attribute__((ext_vector_type(4)));

__device__ __forceinline__ short f2bf(float f) {          // RNE
  union { float f; uint32_t u; } a; a.f = f;
  uint32_t r = a.u + 0x7fffu + ((a.u >> 16) & 1u);
  return (short)(r >> 16);
}
__device__ __forceinline__ float bf2f(short s) {
  union { uint32_t u; float f; } a; a.u = ((uint32_t)(uint16_t)s) << 16;
  return a.f;
}
__device__ __forceinline__ uint32_t pack2bf(float a, float b) {  // trunc pack
  union { float f; uint32_t u; } x, y; x.f = a; y.f = b;
  return (x.u >> 16) | (y.u & 0xffff0000u);
}
__device__ __forceinline__ float fast_exp2(float x) {
#if __has_builtin(__builtin_amdgcn_exp2f)
  return __builtin_amdgcn_exp2f(x);
#else
  return exp2f(x);
#endif
}
__device__ __forceinline__ void async16(const void* g, void* l) {
  __builtin_amdgcn_global_load_lds(
      (const __attribute__((address_space(1))) uint32_t*)g,
      (__attribute__((address_space(3))) uint32_t*)l, 16, 0, 0);
}
#define MFMA(a, b, c) __builtin_amdgcn_mfma_f32_16x16x32_bf16((a), (b), (c), 0, 0, 0)

// ---------------------------------------------------------------------------
// 1) split x (fp32) -> xhi, xlo bf16
// ---------------------------------------------------------------------------
__global__ void k_split_x(const float* __restrict__ x, short* __restrict__ xhi,
                          short* __restrict__ xlo) {
  int i = blockIdx.x * 256 + threadIdx.x;
  float4 v = ((const float4*)x)[i];
  short4 h, l;
  h.x = f2bf(v.x); l.x = f2bf(v.x - bf2f(h.x));
  h.y = f2bf(v.y); l.y = f2bf(v.y - bf2f(h.y));
  h.z = f2bf(v.z); l.z = f2bf(v.z - bf2f(h.z));
  h.w = f2bf(v.w); l.w = f2bf(v.w - bf2f(h.w));
  ((short4*)xhi)[i] = h;
  ((short4*)xlo)[i] = l;
}

// ---------------------------------------------------------------------------
// 2) W[k][n] fp32 -> Wt[n][k] bf16. q,k,v -> whi[z*1M]; o -> wo (separate).
// ---------------------------------------------------------------------------
__global__ void k_prep_w(const float* __restrict__ Wq, const float* __restrict__ Wk,
                         const float* __restrict__ Wv, const float* __restrict__ Wo,
                         short* __restrict__ whi, short* __restrict__ wo) {
  __shared__ float T[64][65];
  int z = blockIdx.z;
  const float* W = (z == 0) ? Wq : (z == 1) ? Wk : (z == 2) ? Wv : Wo;
  int n0 = blockIdx.x * 64, k0 = blockIdx.y * 64;
  int t = threadIdx.x;
  int rr = t >> 4, cc = (t & 15) * 4;
#pragma unroll
  for (int it = 0; it < 4; ++it) {
    int row = rr + it * 16;
    float4 v = *(const float4*)&W[(size_t)(k0 + row) * 1024 + n0 + cc];
    T[row][cc] = v.x; T[row][cc + 1] = v.y; T[row][cc + 2] = v.z; T[row][cc + 3] = v.w;
  }
  __syncthreads();
  short* oh = (z < 3) ? (whi + (size_t)z * 1048576) : wo;
#pragma unroll
  for (int it = 0; it < 4; ++it) {
    int nrow = rr + it * 16;
    short4 h4;
    h4.x = f2bf(T[cc + 0][nrow]);
    h4.y = f2bf(T[cc + 1][nrow]);
    h4.z = f2bf(T[cc + 2][nrow]);
    h4.w = f2bf(T[cc + 3][nrow]);
    *(short4*)&oh[(size_t)(n0 + nrow) * 1024 + k0 + cc] = h4;
  }
}

// ---------------------------------------------------------------------------
// 3) fused QKV projection GEMM (dbuf, single barrier/k-step).
//    Q-proj scaled by LOG2E. V blocks write Vt TRANSPOSED directly.
// ---------------------------------------------------------------------------
__global__ __launch_bounds__(256, 3) void k_gemm_qkv(
    const short* __restrict__ xhi, const short* __restrict__ xlo,
    const short* __restrict__ whi,
    const float* __restrict__ bq, const float* __restrict__ bk,
    const float* __restrict__ bv,
    short* __restrict__ Qhi, short* __restrict__ Qlo,
    short* __restrict__ Khi, short* __restrict__ Klo,
    short* __restrict__ Vt) {
  __shared__ short AH[2][4096];
  __shared__ short AL[2][4096];
  __shared__ short BH[2][4096];
  int tid = threadIdx.x;
  int bx = blockIdx.x;                 // 0..23 ; z = bx>>3 : 0=Q 1=K 2=V
  int m0 = blockIdx.y * 128;
  int n0g = bx * 128;
  bool SPLIT = (bx < 16);
  int w = tid >> 6, lane = tid & 63, lr = lane & 15, lq = lane >> 4;
  int wm = w >> 1, wn = w & 1;
  f32x4 acc[4][4] = {};

  auto stage = [&](int ks, int pb) {
#pragma unroll
    for (int it = 0; it < 2; ++it) {
      int idx = it * 256 + tid;
      int row = idx >> 2, c = idx & 3;
      int cs = c ^ (row & 3);
      size_t ga = (size_t)(m0 + row) * 1024 + ks * 32 + cs * 8;
      async16(xhi + ga, &AH[pb][idx * 8]);
      if (SPLIT) async16(xlo + ga, &AL[pb][idx * 8]);
      size_t gb = (size_t)(n0g + row) * 1024 + ks * 32 + cs * 8;
      async16(whi + gb, &BH[pb][idx * 8]);
    }
  };

  stage(0, 0);
  int p = 0;
  int g = lq ^ (lr & 3);
  for (int ks = 0; ks < 32; ++ks) {
    __syncthreads();
    if (ks < 31) stage(ks + 1, p ^ 1);
    const bf16x8* A8 = (const bf16x8*)AH[p];
    const bf16x8* L8 = (const bf16x8*)AL[p];
    const bf16x8* B8 = (const bf16x8*)BH[p];
    bf16x8 af[4], al[4], bfr[4];
#pragma unroll
    for (int mt = 0; mt < 4; ++mt) af[mt] = A8[(wm * 64 + mt * 16 + lr) * 4 + g];
#pragma unroll
    for (int nt = 0; nt < 4; ++nt) bfr[nt] = B8[(wn * 64 + nt * 16 + lr) * 4 + g];
    if (SPLIT) {
#pragma unroll
      for (int mt = 0; mt < 4; ++mt) al[mt] = L8[(wm * 64 + mt * 16 + lr) * 4 + g];
    }
#pragma unroll
    for (int mt = 0; mt < 4; ++mt)
#pragma unroll
      for (int nt = 0; nt < 4; ++nt)
        acc[mt][nt] = MFMA(af[mt], bfr[nt], acc[mt][nt]);
    if (SPLIT) {
#pragma unroll
      for (int mt = 0; mt < 4; ++mt)
#pragma unroll
        for (int nt = 0; nt < 4; ++nt)
          acc[mt][nt] = MFMA(al[mt], bfr[nt], acc[mt][nt]);
    }
    p ^= 1;
  }

  int z = bx >> 3;
  const float LOG2E = 1.44269504f;
  if (z == 2) {
    // V: write transposed Vt[(b*16+h)*64+dk][s], bias fused, short4 packs
#pragma unroll
    for (int nt = 0; nt < 4; ++nt) {
      int dg = (n0g & 1023) + wn * 64 + nt * 16 + lr;
      float bvv = bv[dg];
      int hh = dg >> 6, dk = dg & 63;
#pragma unroll
      for (int mt = 0; mt < 4; ++mt) {
        int row = m0 + wm * 64 + mt * 16 + lq * 4;
        int b_ = row >> 11, s_ = row & 2047;
        short4 pk;
        pk.x = f2bf(acc[mt][nt][0] + bvv);
        pk.y = f2bf(acc[mt][nt][1] + bvv);
        pk.z = f2bf(acc[mt][nt][2] + bvv);
        pk.w = f2bf(acc[mt][nt][3] + bvv);
        *(short4*)&Vt[(size_t)((b_ * 16 + hh) * 64 + dk) * 2048 + s_] = pk;
      }
    }
  } else {
    const float* bias = (z == 0) ? bq : bk;
    short* Ch = (z == 0) ? Qhi : Khi;
    short* Cl = (z == 0) ? Qlo : Klo;
#pragma unroll
    for (int nt = 0; nt < 4; ++nt) {
      int colg = (n0g & 1023) + wn * 64 + nt * 16 + lr;
      float bvv = bias[colg];
#pragma unroll
      for (int mt = 0; mt < 4; ++mt)
#pragma unroll
        for (int r = 0; r < 4; ++r) {
          int row = m0 + wm * 64 + mt * 16 + lq * 4 + r;
          float v = acc[mt][nt][r] + bvv;
          if (z == 0) v *= LOG2E;       // base-2 softmax folding
          size_t o = (size_t)row * 1024 + colg;
          short hh = f2bf(v);
          Ch[o] = hh;
          Cl[o] = f2bf(v - bf2f(hh));
        }
    }
  }
}

// ---------------------------------------------------------------------------
// 4) O-projection GEMM: out = Obuf @ Wo^T + bo, fp32 out.
// ---------------------------------------------------------------------------
__global__ __launch_bounds__(256, 2) void k_gemm_o(
    const short* __restrict__ Ab, const short* __restrict__ Bb,
    const float* __restrict__ bias, float* __restrict__ Cf) {
  __shared__ short AH[2][4096];
  __shared__ short BH[2][4096];
  int tid = threadIdx.x;
  int m0 = blockIdx.y * 128, n0 = blockIdx.x * 128;
  int w = tid >> 6, lane = tid & 63, lr = lane & 15, lq = lane >> 4;
  int wm = w >> 1, wn = w & 1;
  f32x4 acc[4][4] = {};

  auto stage = [&](int ks, int pb) {
#pragma unroll
    for (int it = 0; it < 2; ++it) {
      int idx = it * 256 + tid;
      int row = idx >> 2, c = idx & 3;
      int cs = c ^ (row & 3);
      async16(Ab + (size_t)(m0 + row) * 1024 + ks * 32 + cs * 8, &AH[pb][idx * 8]);
      async16(Bb + (size_t)(n0 + row) * 1024 + ks * 32 + cs * 8, &BH[pb][idx * 8]);
    }
  };

  stage(0, 0);
  int p = 0;
  int g = lq ^ (lr & 3);
  for (int ks = 0; ks < 32; ++ks) {
    __syncthreads();
    if (ks < 31) stage(ks + 1, p ^ 1);
    const bf16x8* A8 = (const bf16x8*)AH[p];
    const bf16x8* B8 = (const bf16x8*)BH[p];
    bf16x8 af[4], bfr[4];
#pragma unroll
    for (int mt = 0; mt < 4; ++mt) af[mt] = A8[(wm * 64 + mt * 16 + lr) * 4 + g];
#pragma unroll
    for (int nt = 0; nt < 4; ++nt) bfr[nt] = B8[(wn * 64 + nt * 16 + lr) * 4 + g];
#pragma unroll
    for (int mt = 0; mt < 4; ++mt)
#pragma unroll
      for (int nt = 0; nt < 4; ++nt)
        acc[mt][nt] = MFMA(af[mt], bfr[nt], acc[mt][nt]);
    p ^= 1;
  }
#pragma unroll
  for (int nt = 0; nt < 4; ++nt) {
    int col = n0 + wn * 64 + nt * 16 + lr;
    float bvv = bias[col];
#pragma unroll
    for (int mt = 0; mt < 4; ++mt)
#pragma unroll
      for (int r = 0; r < 4; ++r) {
        int row = m0 + wm * 64 + mt * 16 + lq * 4 + r;
        Cf[(size_t)row * 1024 + col] = acc[mt][nt][r] + bvv;
      }
  }
}

// ---------------------------------------------------------------------------
// 5) flash attention. Paired bands (iA=pr, iB=31-pr) + j-parity split via
//    blockIdx.y -> 1024 uniform blocks (16-17 band-tile units), all resident
//    (4/CU, LDS 24KB). S^T QK, bpermute PV, unnormalized partials.
//    ls partials are PER (b,h,s): lsp[bh*2048 + s].
// ---------------------------------------------------------------------------
__global__ __launch_bounds__(256, 4) void k_attn(
    const short* __restrict__ Khi, const short* __restrict__ Klo,
    const short* __restrict__ Qhi, const short* __restrict__ Qlo,
    const short* __restrict__ Vt, const int* __restrict__ amask,
    short* __restrict__ O0, float* __restrict__ ls0,
    short* __restrict__ O1, float* __restrict__ ls1) {
  __shared__ short QH[4096];        // keys-role hi: [j 64][d 64] swizzled
  __shared__ short QL[4096];
  __shared__ short VS[4096];        // V^T tile: [d 64][j 64] swizzled
  int tid = threadIdx.x;
  int pr = blockIdx.x;              // 0..15
  int z  = blockIdx.y;              // j-tile parity
  int bh = blockIdx.z, b = bh >> 4, h = bh & 15;
  int w = tid >> 6, lane = tid & 63, lr = lane & 15, lq = lane >> 4;
  int iA = pr, iB = 31 - pr;
  short* Op  = z ? O1 : O0;
  float* lsp = z ? ls1 : ls0;

  // query-role B-fragments (K-proj rows), hi+lo, both bands, registers
  bf16x8 khA[2], klA[2], khB[2], klB[2];
  {
    size_t ra = ((size_t)(b * 2048 + iA * 64 + w * 16 + lr)) * 1024 + h * 64;
    size_t rb = ((size_t)(b * 2048 + iB * 64 + w * 16 + lr)) * 1024 + h * 64;
#pragma unroll
    for (int ks = 0; ks < 2; ++ks) {
      khA[ks] = *(const bf16x8*)(Khi + ra + ks * 32 + lq * 8);
      klA[ks] = *(const bf16x8*)(Klo + ra + ks * 32 + lq * 8);
      khB[ks] = *(const bf16x8*)(Khi + rb + ks * 32 + lq * 8);
      klB[ks] = *(const bf16x8*)(Klo + rb + ks * 32 + lq * 8);
    }
  }

  f32x4 OA[4] = {}, OB[4] = {};
  float lsA = 0.f, lsB = 0.f;       // per-lane partial rowsum (query = lr)
  int iqA = iA * 64 + w * 16 + lr;
  int iqB = iB * 64 + w * 16 + lr;
  int baddr0 = (((lq & 1) * 2) * 16 + lr) * 4;   // bpermute byte addrs
  int baddr1 = baddr0 + 64;

  auto stage = [&](int jt) {
    int j0 = jt * 64;
#pragma unroll
    for (int it = 0; it < 2; ++it) {
      int idx = it * 256 + tid;
      int rr = idx >> 3, c = idx & 7;
      int cs = c ^ (rr & 7);
      size_t gq = ((size_t)(b * 2048 + j0 + rr)) * 1024 + h * 64 + cs * 8;
      async16(Qhi + gq, &QH[idx * 8]);
      async16(Qlo + gq, &QL[idx * 8]);
      size_t gv = ((size_t)(bh * 64 + rr)) * 2048 + j0 + cs * 8;
      async16(Vt + gv, &VS[idx * 8]);
    }
  };

  const bf16x8* Q8 = (const bf16x8*)QH;
  const bf16x8* L8 = (const bf16x8*)QL;
  const bf16x8* V8 = (const bf16x8*)VS;

  for (int jt = z; jt <= iB; jt += 2) {
    stage(jt);
    __syncthreads();                // staged tile ready
    bool DUAL = (jt <= iA);
    int j0 = jt * 64;

    int av = amask[b * 2048 + j0 + lane];
    unsigned long long bal = __ballot(av != 0);
    bool allv = (bal == ~0ull);

    // S^T: rows j (4 mt), cols q (lr). 3-term split, A-frags shared.
    f32x4 sA[4] = {}, sB[4] = {};
#pragma unroll
    for (int mt = 0; mt < 4; ++mt) {
      int row = mt * 16 + lr;
#pragma unroll
      for (int ks = 0; ks < 2; ++ks) {
        int gi = row * 8 + ((ks * 4 + lq) ^ (row & 7));
        bf16x8 qa = Q8[gi];
        bf16x8 la = L8[gi];
        sB[mt] = MFMA(qa, khB[ks], sB[mt]);
        sB[mt] = MFMA(la, khB[ks], sB[mt]);
        sB[mt] = MFMA(qa, klB[ks], sB[mt]);
        if (DUAL) {
          sA[mt] = MFMA(qa, khA[ks], sA[mt]);
          sA[mt] = MFMA(la, khA[ks], sA[mt]);
          sA[mt] = MFMA(qa, klA[ks], sA[mt]);
        }
      }
    }

    auto band_pv = [&](f32x4* s, f32x4* O, float& ls, int iq, bool diag) {
      float pv[4][4];
#pragma unroll
      for (int mt = 0; mt < 4; ++mt)
#pragma unroll
        for (int r = 0; r < 4; ++r)
          pv[mt][r] = fast_exp2(s[mt][r]);
      if (diag) {
#pragma unroll
        for (int mt = 0; mt < 4; ++mt)
#pragma unroll
          for (int r = 0; r < 4; ++r)
            if (j0 + mt * 16 + lq * 4 + r > iq) pv[mt][r] = 0.f;
      }
      if (!allv) {
#pragma unroll
        for (int mt = 0; mt < 4; ++mt)
#pragma unroll
          for (int r = 0; r < 4; ++r)
            if (!((bal >> (mt * 16 + lq * 4 + r)) & 1)) pv[mt][r] = 0.f;
      }
      uint32_t pd[4][2];
#pragma unroll
      for (int mt = 0; mt < 4; ++mt) {
        ls += (pv[mt][0] + pv[mt][1]) + (pv[mt][2] + pv[mt][3]);
        pd[mt][0] = pack2bf(pv[mt][0], pv[mt][1]);
        pd[mt][1] = pack2bf(pv[mt][2], pv[mt][3]);
      }
#pragma unroll
      for (int k2 = 0; k2 < 2; ++k2) {
        union { int i[4]; bf16x8 v; } pa;
#pragma unroll
        for (int dd = 0; dd < 4; ++dd) {
          int addr = (dd >> 1) ? baddr1 : baddr0;
          int v0 = __builtin_amdgcn_ds_bpermute(addr, (int)pd[k2 * 2 + 0][dd & 1]);
          int v1 = __builtin_amdgcn_ds_bpermute(addr, (int)pd[k2 * 2 + 1][dd & 1]);
          pa.i[dd] = (lq >> 1) ? v1 : v0;
        }
#pragma unroll
        for (int nt = 0; nt < 4; ++nt) {
          int row = nt * 16 + lr;
          bf16x8 vb = V8[row * 8 + ((k2 * 4 + lq) ^ (row & 7))];
          O[nt] = MFMA(pa.v, vb, O[nt]);
        }
      }
    };

    band_pv(sB, OB, lsB, iqB, jt == iB);
    if (DUAL) band_pv(sA, OA, lsA, iqA, jt == iA);
    __syncthreads();                // reads done before next stage
  }

  // epilogue: store unnormalized partials (bf16 O, f32 ls per (b,h,s))
  auto fin = [&](f32x4* O, float ls, int i0) {
    float t = ls;
    t += __shfl_xor(t, 16);
    t += __shfl_xor(t, 32);
    if (lq == 0) lsp[bh * 2048 + i0 + w * 16 + lr] = t;   // per-head!
#pragma unroll
    for (int nt = 0; nt < 4; ++nt)
#pragma unroll
      for (int r = 0; r < 4; ++r) {
        int row = b * 2048 + i0 + w * 16 + lq * 4 + r;
        int col = h * 64 + nt * 16 + lr;
        Op[(size_t)row * 1024 + col] = f2bf(O[nt][r]);
      }
  };
  fin(OA, lsA, iA * 64);
  fin(OB, lsB, iB * 64);
}

// ---------------------------------------------------------------------------
// 6) merge partials: Obuf = (O0 + O1) / (ls0 + ls1), bf16 out.
//    ls indexed per (b,h,s).
// ---------------------------------------------------------------------------
__global__ void k_merge(const short* __restrict__ O0, const short* __restrict__ O1,
                        const float* __restrict__ ls0, const float* __restrict__ ls1,
                        short* __restrict__ Obuf) {
  int idx = blockIdx.x * 256 + threadIdx.x;   // one bf16x8 per thread
  int row = idx >> 7;                          // b*2048+s (128 vec8 per row)
  int h = (idx >> 3) & 15;                     // head of this col block
  int lsrow = ((row >> 11) * 16 + h) * 2048 + (row & 2047);
  float inv = 1.0f / (ls0[lsrow] + ls1[lsrow]);
  bf16x8 a = ((const bf16x8*)O0)[idx];
  bf16x8 c = ((const bf16x8*)O1)[idx];
  bf16x8 o;
#pragma unroll
  for (int j = 0; j < 8; ++j)
    o[j] = f2bf((bf2f(a[j]) + bf2f(c[j])) * inv);
  ((bf16x8*)Obuf)[idx] = o;
}

// ---------------------------------------------------------------------------
// launcher
// ---------------------------------------------------------------------------
extern "C" void kernel_launch(void* const* d_in, const int* in_sizes, int n_in,
                              void* d_out, int out_size, void* d_ws, size_t ws_size,
                              hipStream_t stream) {
  const float* x  = (const float*)d_in[0];
  const int* amask = (const int*)d_in[1];
  const float* Wq = (const float*)d_in[2];
  const float* bq = (const float*)d_in[3];
  const float* Wk = (const float*)d_in[4];
  const float* bk = (const float*)d_in[5];
  const float* Wv = (const float*)d_in[6];
  const float* bv = (const float*)d_in[7];
  const float* Wo = (const float*)d_in[8];
  const float* bo = (const float*)d_in[9];

  char* ws = (char*)d_ws;
  const size_t MB = 1024 * 1024;
  short* xhi = (short*)(ws);             // 0..8MB
  short* xlo = (short*)(ws + 8 * MB);    // 8..16; dead after qkv -> O1
  short* whi = (short*)(ws + 16 * MB);   // 16..22 (q,k,v); dead after qkv -> O0
  float* ls0 = (float*)(ws + 24 * MB);   // 256KB (per b,h,s = 32*2048 floats)
  float* ls1 = (float*)(ws + 25 * MB);   // 256KB
  short* wo  = (short*)(ws + 26 * MB);   // 26..28
  short* Qhi = (short*)(ws + 28 * MB);   // dead after attn -> merged Obuf
  short* Qlo = (short*)(ws + 36 * MB);
  short* Khi = (short*)(ws + 44 * MB);
  short* Klo = (short*)(ws + 52 * MB);
  short* Vt  = (short*)(ws + 60 * MB);   // total 68MB
  short* O0   = whi;
  short* O1   = xlo;
  short* Obuf = Qhi;

  k_split_x<<<4096, 256, 0, stream>>>(x, xhi, xlo);
  k_prep_w<<<dim3(16, 16, 4), 256, 0, stream>>>(Wq, Wk, Wv, Wo, whi, wo);

  k_gemm_qkv<<<dim3(24, 32), 256, 0, stream>>>(xhi, xlo, whi, bq, bk, bv,
                                               Qhi, Qlo, Khi, Klo, Vt);
  k_attn<<<dim3(16, 2, 32), 256, 0, stream>>>(Khi, Klo, Qhi, Qlo, Vt, amask,
                                              O0, ls0, O1, ls1);
  k_merge<<<2048, 256, 0, stream>>>(O0, O1, ls0, ls1, Obuf);
  k_gemm_o<<<dim3(8, 32), 256, 0, stream>>>(Obuf, wo, bo, (float*)d_out);
}

// Round 7
// 241.667 us; speedup vs baseline: 1.2336x; 1.2336x over previous
//
#include <hip/hip_runtime.h>
#include <stdint.h>
#include <stddef.h>

// ---------------------------------------------------------------------------
// MaskedMultiHeadAttn: B=2, S=2048, D=1024, H=16, DK=64, fp32 in/out.
// scores = K·Q^T (roles swapped), NO 1/sqrt(dk) scale, causal+pad mask.
// R7: k_attn redesign — 32-row bands paired (p, 63-p), 128-thr blocks,
//     1024 all-resident blocks (4/CU, 4 de-phased barrier groups/CU),
//     UNIFORM 33 iterations/block (band A tiles then band B tiles, diagonal
//     = last tile of each phase), XCD swizzle for L2 locality, in-kernel
//     normalize (no partials/merge), S^T QK + bpermute PV, 3-term split.
// ---------------------------------------------------------------------------

typedef short bf16x8 __attribute__((ext_vector_type(8)));  // 8 bf16 = 4 VGPR
typedef float f32x4  __attribute__((ext_vector_type(4)));

__device__ __forceinline__ short f2bf(float f) {          // RNE
  union { float f; uint32_t u; } a; a.f = f;
  uint32_t r = a.u + 0x7fffu + ((a.u >> 16) & 1u);
  return (short)(r >> 16);
}
__device__ __forceinline__ float bf2f(short s) {
  union { uint32_t u; float f; } a; a.u = ((uint32_t)(uint16_t)s) << 16;
  return a.f;
}
__device__ __forceinline__ uint32_t pack2bf(float a, float b) {  // trunc pack
  union { float f; uint32_t u; } x, y; x.f = a; y.f = b;
  return (x.u >> 16) | (y.u & 0xffff0000u);
}
__device__ __forceinline__ float fast_exp2(float x) {
#if __has_builtin(__builtin_amdgcn_exp2f)
  return __builtin_amdgcn_exp2f(x);
#else
  return exp2f(x);
#endif
}
__device__ __forceinline__ void async16(const void* g, void* l) {
  __builtin_amdgcn_global_load_lds(
      (const __attribute__((address_space(1))) uint32_t*)g,
      (__attribute__((address_space(3))) uint32_t*)l, 16, 0, 0);
}
#define MFMA(a, b, c) __builtin_amdgcn_mfma_f32_16x16x32_bf16((a), (b), (c), 0, 0, 0)

// ---------------------------------------------------------------------------
// 1) split x (fp32) -> xhi, xlo bf16
// ---------------------------------------------------------------------------
__global__ void k_split_x(const float* __restrict__ x, short* __restrict__ xhi,
                          short* __restrict__ xlo) {
  int i = blockIdx.x * 256 + threadIdx.x;
  float4 v = ((const float4*)x)[i];
  short4 h, l;
  h.x = f2bf(v.x); l.x = f2bf(v.x - bf2f(h.x));
  h.y = f2bf(v.y); l.y = f2bf(v.y - bf2f(h.y));
  h.z = f2bf(v.z); l.z = f2bf(v.z - bf2f(h.z));
  h.w = f2bf(v.w); l.w = f2bf(v.w - bf2f(h.w));
  ((short4*)xhi)[i] = h;
  ((short4*)xlo)[i] = l;
}

// ---------------------------------------------------------------------------
// 2) W[k][n] fp32 -> Wt[n][k] bf16. q,k,v -> whi[z*1M]; o -> wo (separate).
// ---------------------------------------------------------------------------
__global__ void k_prep_w(const float* __restrict__ Wq, const float* __restrict__ Wk,
                         const float* __restrict__ Wv, const float* __restrict__ Wo,
                         short* __restrict__ whi, short* __restrict__ wo) {
  __shared__ float T[64][65];
  int z = blockIdx.z;
  const float* W = (z == 0) ? Wq : (z == 1) ? Wk : (z == 2) ? Wv : Wo;
  int n0 = blockIdx.x * 64, k0 = blockIdx.y * 64;
  int t = threadIdx.x;
  int rr = t >> 4, cc = (t & 15) * 4;
#pragma unroll
  for (int it = 0; it < 4; ++it) {
    int row = rr + it * 16;
    float4 v = *(const float4*)&W[(size_t)(k0 + row) * 1024 + n0 + cc];
    T[row][cc] = v.x; T[row][cc + 1] = v.y; T[row][cc + 2] = v.z; T[row][cc + 3] = v.w;
  }
  __syncthreads();
  short* oh = (z < 3) ? (whi + (size_t)z * 1048576) : wo;
#pragma unroll
  for (int it = 0; it < 4; ++it) {
    int nrow = rr + it * 16;
    short4 h4;
    h4.x = f2bf(T[cc + 0][nrow]);
    h4.y = f2bf(T[cc + 1][nrow]);
    h4.z = f2bf(T[cc + 2][nrow]);
    h4.w = f2bf(T[cc + 3][nrow]);
    *(short4*)&oh[(size_t)(n0 + nrow) * 1024 + k0 + cc] = h4;
  }
}

// ---------------------------------------------------------------------------
// 3) fused QKV projection GEMM (dbuf, single barrier/k-step).
//    Q-proj scaled by LOG2E. V blocks write Vt TRANSPOSED directly.
// ---------------------------------------------------------------------------
__global__ __launch_bounds__(256, 3) void k_gemm_qkv(
    const short* __restrict__ xhi, const short* __restrict__ xlo,
    const short* __restrict__ whi,
    const float* __restrict__ bq, const float* __restrict__ bk,
    const float* __restrict__ bv,
    short* __restrict__ Qhi, short* __restrict__ Qlo,
    short* __restrict__ Khi, short* __restrict__ Klo,
    short* __restrict__ Vt) {
  __shared__ short AH[2][4096];
  __shared__ short AL[2][4096];
  __shared__ short BH[2][4096];
  int tid = threadIdx.x;
  int bx = blockIdx.x;                 // 0..23 ; z = bx>>3 : 0=Q 1=K 2=V
  int m0 = blockIdx.y * 128;
  int n0g = bx * 128;
  bool SPLIT = (bx < 16);
  int w = tid >> 6, lane = tid & 63, lr = lane & 15, lq = lane >> 4;
  int wm = w >> 1, wn = w & 1;
  f32x4 acc[4][4] = {};

  auto stage = [&](int ks, int pb) {
#pragma unroll
    for (int it = 0; it < 2; ++it) {
      int idx = it * 256 + tid;
      int row = idx >> 2, c = idx & 3;
      int cs = c ^ (row & 3);
      size_t ga = (size_t)(m0 + row) * 1024 + ks * 32 + cs * 8;
      async16(xhi + ga, &AH[pb][idx * 8]);
      if (SPLIT) async16(xlo + ga, &AL[pb][idx * 8]);
      size_t gb = (size_t)(n0g + row) * 1024 + ks * 32 + cs * 8;
      async16(whi + gb, &BH[pb][idx * 8]);
    }
  };

  stage(0, 0);
  int p = 0;
  int g = lq ^ (lr & 3);
  for (int ks = 0; ks < 32; ++ks) {
    __syncthreads();
    if (ks < 31) stage(ks + 1, p ^ 1);
    const bf16x8* A8 = (const bf16x8*)AH[p];
    const bf16x8* L8 = (const bf16x8*)AL[p];
    const bf16x8* B8 = (const bf16x8*)BH[p];
    bf16x8 af[4], al[4], bfr[4];
#pragma unroll
    for (int mt = 0; mt < 4; ++mt) af[mt] = A8[(wm * 64 + mt * 16 + lr) * 4 + g];
#pragma unroll
    for (int nt = 0; nt < 4; ++nt) bfr[nt] = B8[(wn * 64 + nt * 16 + lr) * 4 + g];
    if (SPLIT) {
#pragma unroll
      for (int mt = 0; mt < 4; ++mt) al[mt] = L8[(wm * 64 + mt * 16 + lr) * 4 + g];
    }
#pragma unroll
    for (int mt = 0; mt < 4; ++mt)
#pragma unroll
      for (int nt = 0; nt < 4; ++nt)
        acc[mt][nt] = MFMA(af[mt], bfr[nt], acc[mt][nt]);
    if (SPLIT) {
#pragma unroll
      for (int mt = 0; mt < 4; ++mt)
#pragma unroll
        for (int nt = 0; nt < 4; ++nt)
          acc[mt][nt] = MFMA(al[mt], bfr[nt], acc[mt][nt]);
    }
    p ^= 1;
  }

  int z = bx >> 3;
  const float LOG2E = 1.44269504f;
  if (z == 2) {
    // V: write transposed Vt[(b*16+h)*64+dk][s], bias fused, short4 packs
#pragma unroll
    for (int nt = 0; nt < 4; ++nt) {
      int dg = (n0g & 1023) + wn * 64 + nt * 16 + lr;
      float bvv = bv[dg];
      int hh = dg >> 6, dk = dg & 63;
#pragma unroll
      for (int mt = 0; mt < 4; ++mt) {
        int row = m0 + wm * 64 + mt * 16 + lq * 4;
        int b_ = row >> 11, s_ = row & 2047;
        short4 pk;
        pk.x = f2bf(acc[mt][nt][0] + bvv);
        pk.y = f2bf(acc[mt][nt][1] + bvv);
        pk.z = f2bf(acc[mt][nt][2] + bvv);
        pk.w = f2bf(acc[mt][nt][3] + bvv);
        *(short4*)&Vt[(size_t)((b_ * 16 + hh) * 64 + dk) * 2048 + s_] = pk;
      }
    }
  } else {
    const float* bias = (z == 0) ? bq : bk;
    short* Ch = (z == 0) ? Qhi : Khi;
    short* Cl = (z == 0) ? Qlo : Klo;
#pragma unroll
    for (int nt = 0; nt < 4; ++nt) {
      int colg = (n0g & 1023) + wn * 64 + nt * 16 + lr;
      float bvv = bias[colg];
#pragma unroll
      for (int mt = 0; mt < 4; ++mt)
#pragma unroll
        for (int r = 0; r < 4; ++r) {
          int row = m0 + wm * 64 + mt * 16 + lq * 4 + r;
          float v = acc[mt][nt][r] + bvv;
          if (z == 0) v *= LOG2E;       // base-2 softmax folding
          size_t o = (size_t)row * 1024 + colg;
          short hh = f2bf(v);
          Ch[o] = hh;
          Cl[o] = f2bf(v - bf2f(hh));
        }
    }
  }
}

// ---------------------------------------------------------------------------
// 4) O-projection GEMM: out = Obuf @ Wo^T + bo, fp32 out.
// ---------------------------------------------------------------------------
__global__ __launch_bounds__(256, 2) void k_gemm_o(
    const short* __restrict__ Ab, const short* __restrict__ Bb,
    const float* __restrict__ bias, float* __restrict__ Cf) {
  __shared__ short AH[2][4096];
  __shared__ short BH[2][4096];
  int tid = threadIdx.x;
  int m0 = blockIdx.y * 128, n0 = blockIdx.x * 128;
  int w = tid >> 6, lane = tid & 63, lr = lane & 15, lq = lane >> 4;
  int wm = w >> 1, wn = w & 1;
  f32x4 acc[4][4] = {};

  auto stage = [&](int ks, int pb) {
#pragma unroll
    for (int it = 0; it < 2; ++it) {
      int idx = it * 256 + tid;
      int row = idx >> 2, c = idx & 3;
      int cs = c ^ (row & 3);
      async16(Ab + (size_t)(m0 + row) * 1024 + ks * 32 + cs * 8, &AH[pb][idx * 8]);
      async16(Bb + (size_t)(n0 + row) * 1024 + ks * 32 + cs * 8, &BH[pb][idx * 8]);
    }
  };

  stage(0, 0);
  int p = 0;
  int g = lq ^ (lr & 3);
  for (int ks = 0; ks < 32; ++ks) {
    __syncthreads();
    if (ks < 31) stage(ks + 1, p ^ 1);
    const bf16x8* A8 = (const bf16x8*)AH[p];
    const bf16x8* B8 = (const bf16x8*)BH[p];
    bf16x8 af[4], bfr[4];
#pragma unroll
    for (int mt = 0; mt < 4; ++mt) af[mt] = A8[(wm * 64 + mt * 16 + lr) * 4 + g];
#pragma unroll
    for (int nt = 0; nt < 4; ++nt) bfr[nt] = B8[(wn * 64 + nt * 16 + lr) * 4 + g];
#pragma unroll
    for (int mt = 0; mt < 4; ++mt)
#pragma unroll
      for (int nt = 0; nt < 4; ++nt)
        acc[mt][nt] = MFMA(af[mt], bfr[nt], acc[mt][nt]);
    p ^= 1;
  }
#pragma unroll
  for (int nt = 0; nt < 4; ++nt) {
    int col = n0 + wn * 64 + nt * 16 + lr;
    float bvv = bias[col];
#pragma unroll
    for (int mt = 0; mt < 4; ++mt)
#pragma unroll
      for (int r = 0; r < 4; ++r) {
        int row = m0 + wm * 64 + mt * 16 + lq * 4 + r;
        Cf[(size_t)row * 1024 + col] = acc[mt][nt][r] + bvv;
      }
  }
}

// ---------------------------------------------------------------------------
// 5) flash attention. Block = (p, bh) via XCD swizzle; bands A=p, B=63-p
//    (32-row). 128 threads = 2 waves; wave w handles rows w*16..w*16+15 of
//    the active band. Phase 1: band A tiles 0..nA-1; phase 2: band B tiles
//    0..nB-1 (nA+nB == 33 for all p -> uniform duration, all-resident grid).
//    Diagonal tile == last tile of each phase. S^T QK (3-term split),
//    bpermute P-transform, PV, in-kernel normalize.
// ---------------------------------------------------------------------------
__global__ __launch_bounds__(128, 2) void k_attn(
    const short* __restrict__ Khi, const short* __restrict__ Klo,
    const short* __restrict__ Qhi, const short* __restrict__ Qlo,
    const short* __restrict__ Vt, const int* __restrict__ amask,
    short* __restrict__ Obuf) {
  __shared__ short QH[4096];        // keys-role hi: [j 64][d 64] swizzled
  __shared__ short QL[4096];
  __shared__ short VS[4096];        // V^T tile: [d 64][j 64] swizzled
  int tid = threadIdx.x;
  int bid = blockIdx.x;             // 0..1023
  int xcd = bid & 7, slot = bid >> 3;
  int bh = xcd * 4 + (slot >> 5);   // 4 heads per XCD for L2 locality
  int p  = slot & 31;               // band pair id; p ascending = long-first
  int b = bh >> 4, h = bh & 15;
  int w = tid >> 6, lane = tid & 63, lr = lane & 15, lq = lane >> 4;
  int bandA = p, bandB = 63 - p;
  int nA = ((p * 32 + 31) >> 6) + 1;           // A-phase tile count
  // total iterations = 33 for every p (nB = 33 - nA)

  f32x4 OA[4] = {}, OB[4] = {};
  float lsA = 0.f, lsB = 0.f;
  int baddr0 = (((lq & 1) * 2) * 16 + lr) * 4; // bpermute byte addrs
  int baddr1 = baddr0 + 64;

  bf16x8 kh[2], kl[2];              // keys-role frags of ACTIVE band
  const bf16x8* Q8 = (const bf16x8*)QH;
  const bf16x8* L8 = (const bf16x8*)QL;
  const bf16x8* V8 = (const bf16x8*)VS;

  for (int t = 0; t < 33; ++t) {
    bool isA = (t < nA);
    int band = isA ? bandA : bandB;
    int jt = isA ? t : t - nA;
    int j0 = jt * 64;
    // ---- stage tile (128 threads, 4 rounds of 16B) ----
#pragma unroll
    for (int it = 0; it < 4; ++it) {
      int idx = it * 128 + tid;     // 0..511
      int rr = idx >> 3, c = idx & 7;
      int cs = c ^ (rr & 7);
      size_t gq = ((size_t)(b * 2048 + j0 + rr)) * 1024 + h * 64 + cs * 8;
      async16(Qhi + gq, &QH[idx * 8]);
      async16(Qlo + gq, &QL[idx * 8]);
      size_t gv = ((size_t)(bh * 64 + rr)) * 2048 + j0 + cs * 8;
      async16(Vt + gv, &VS[idx * 8]);
    }
    // ---- load keys-role register frags at phase starts ----
    if (t == 0 || t == nA) {
      size_t ra = ((size_t)(b * 2048 + band * 32 + w * 16 + lr)) * 1024 + h * 64;
#pragma unroll
      for (int ks = 0; ks < 2; ++ks) {
        kh[ks] = *(const bf16x8*)(Khi + ra + ks * 32 + lq * 8);
        kl[ks] = *(const bf16x8*)(Klo + ra + ks * 32 + lq * 8);
      }
    }
    __syncthreads();                // tile staged

    // padding-mask fast path (wave-level, lane = j0+lane)
    int av = amask[b * 2048 + j0 + lane];
    unsigned long long bal = __ballot(av != 0);
    bool allv = (bal == ~0ull);

    // ---- S^T: rows j (4 mt), cols q (lr). 3-term split. ----
    f32x4 s[4] = {};
#pragma unroll
    for (int mt = 0; mt < 4; ++mt) {
      int row = mt * 16 + lr;
#pragma unroll
      for (int ks = 0; ks < 2; ++ks) {
        int gi = row * 8 + ((ks * 4 + lq) ^ (row & 7));
        bf16x8 qa = Q8[gi];
        bf16x8 la = L8[gi];
        s[mt] = MFMA(qa, kh[ks], s[mt]);
        s[mt] = MFMA(la, kh[ks], s[mt]);
        s[mt] = MFMA(qa, kl[ks], s[mt]);
      }
    }

    // ---- exp2 / masks / rowsum / pack ----
    bool diag = (t == nA - 1) || (t == 32);  // last tile of each phase
    int iq = band * 32 + w * 16 + lr;        // this lane's query (s index)
    float pv[4][4];
#pragma unroll
    for (int mt = 0; mt < 4; ++mt)
#pragma unroll
      for (int r = 0; r < 4; ++r)
        pv[mt][r] = fast_exp2(s[mt][r]);
    if (diag) {
#pragma unroll
      for (int mt = 0; mt < 4; ++mt)
#pragma unroll
        for (int r = 0; r < 4; ++r)
          if (j0 + mt * 16 + lq * 4 + r > iq) pv[mt][r] = 0.f;
    }
    if (!allv) {
#pragma unroll
      for (int mt = 0; mt < 4; ++mt)
#pragma unroll
        for (int r = 0; r < 4; ++r)
          if (!((bal >> (mt * 16 + lq * 4 + r)) & 1)) pv[mt][r] = 0.f;
    }
    uint32_t pd[4][2];
    float lt = 0.f;
#pragma unroll
    for (int mt = 0; mt < 4; ++mt) {
      lt += (pv[mt][0] + pv[mt][1]) + (pv[mt][2] + pv[mt][3]);
      pd[mt][0] = pack2bf(pv[mt][0], pv[mt][1]);
      pd[mt][1] = pack2bf(pv[mt][2], pv[mt][3]);
    }
    if (isA) lsA += lt; else lsB += lt;

    // ---- P^T -> A-frag via bpermute; PV into the active accumulator ----
    f32x4* O = isA ? OA : OB;
#pragma unroll
    for (int k2 = 0; k2 < 2; ++k2) {
      union { int i[4]; bf16x8 v; } pa;
#pragma unroll
      for (int dd = 0; dd < 4; ++dd) {
        int addr = (dd >> 1) ? baddr1 : baddr0;
        int v0 = __builtin_amdgcn_ds_bpermute(addr, (int)pd[k2 * 2 + 0][dd & 1]);
        int v1 = __builtin_amdgcn_ds_bpermute(addr, (int)pd[k2 * 2 + 1][dd & 1]);
        pa.i[dd] = (lq >> 1) ? v1 : v0;
      }
#pragma unroll
      for (int nt = 0; nt < 4; ++nt) {
        int row = nt * 16 + lr;
        bf16x8 vb = V8[row * 8 + ((k2 * 4 + lq) ^ (row & 7))];
        O[nt] = MFMA(pa.v, vb, O[nt]);
      }
    }
    __syncthreads();                // all reads done before next stage
  }

  // ---- epilogue: reduce rowsums over lq, normalize, store both bands ----
  auto fin = [&](f32x4* O, float ls, int band) {
    float tsum = ls;
    tsum += __shfl_xor(tsum, 16);
    tsum += __shfl_xor(tsum, 32);
    float inv[4];
#pragma unroll
    for (int r = 0; r < 4; ++r) inv[r] = 1.0f / __shfl(tsum, lq * 4 + r, 64);
#pragma unroll
    for (int nt = 0; nt < 4; ++nt)
#pragma unroll
      for (int r = 0; r < 4; ++r) {
        int row = b * 2048 + band * 32 + w * 16 + lq * 4 + r;
        int col = h * 64 + nt * 16 + lr;
        Obuf[(size_t)row * 1024 + col] = f2bf(O[nt][r] * inv[r]);
      }
  };
  fin(OA, lsA, bandA);
  fin(OB, lsB, bandB);
}

// ---------------------------------------------------------------------------
// launcher
// ---------------------------------------------------------------------------
extern "C" void kernel_launch(void* const* d_in, const int* in_sizes, int n_in,
                              void* d_out, int out_size, void* d_ws, size_t ws_size,
                              hipStream_t stream) {
  const float* x  = (const float*)d_in[0];
  const int* amask = (const int*)d_in[1];
  const float* Wq = (const float*)d_in[2];
  const float* bq = (const float*)d_in[3];
  const float* Wk = (const float*)d_in[4];
  const float* bk = (const float*)d_in[5];
  const float* Wv = (const float*)d_in[6];
  const float* bv = (const float*)d_in[7];
  const float* Wo = (const float*)d_in[8];
  const float* bo = (const float*)d_in[9];

  char* ws = (char*)d_ws;
  const size_t MB = 1024 * 1024;
  short* xhi = (short*)(ws);             // 0..8MB; dead after qkv -> Obuf
  short* xlo = (short*)(ws + 8 * MB);    // 8..16
  short* whi = (short*)(ws + 16 * MB);   // 16..22 (q,k,v)
  short* wo  = (short*)(ws + 26 * MB);   // 26..28
  short* Qhi = (short*)(ws + 28 * MB);
  short* Qlo = (short*)(ws + 36 * MB);
  short* Khi = (short*)(ws + 44 * MB);
  short* Klo = (short*)(ws + 52 * MB);
  short* Vt  = (short*)(ws + 60 * MB);   // total 68MB
  short* Obuf = xhi;                     // xhi dead after qkv

  k_split_x<<<4096, 256, 0, stream>>>(x, xhi, xlo);
  k_prep_w<<<dim3(16, 16, 4), 256, 0, stream>>>(Wq, Wk, Wv, Wo, whi, wo);

  k_gemm_qkv<<<dim3(24, 32), 256, 0, stream>>>(xhi, xlo, whi, bq, bk, bv,
                                               Qhi, Qlo, Khi, Klo, Vt);
  k_attn<<<1024, 128, 0, stream>>>(Khi, Klo, Qhi, Qlo, Vt, amask, Obuf);
  k_gemm_o<<<dim3(8, 32), 256, 0, stream>>>(Obuf, wo, bo, (float*)d_out);
}

// Round 8
// 239.378 us; speedup vs baseline: 1.2454x; 1.0096x over previous
//
#include <hip/hip_runtime.h>
#include <stdint.h>
#include <stddef.h>

// ---------------------------------------------------------------------------
// MaskedMultiHeadAttn: B=2, S=2048, D=1024, H=16, DK=64, fp32 in/out.
// scores = K·Q^T (roles swapped), NO 1/sqrt(dk) scale, causal+pad mask.
// R8: k_attn — equal-trip 4-wave blocks (bands 2L-2 & 2L-1 share tile count
//     L), 256-thr blocks, staged tile feeds 4 waves (staging/wave halved),
//     double-buffered LDS (48KB -> 3 blocks/CU = 12 waves/CU) with single
//     barrier/iter (prefetch right after barrier), longest-first order per
//     XCD lane, XCD swizzle kept. k_gemm_o re-tiled 128x64 (2 blocks/CU).
// ---------------------------------------------------------------------------

typedef short bf16x8 __attribute__((ext_vector_type(8)));  // 8 bf16 = 4 VGPR
typedef float f32x4  __attribute__((ext_vector_type(4)));

__device__ __forceinline__ short f2bf(float f) {          // RNE
  union { float f; uint32_t u; } a; a.f = f;
  uint32_t r = a.u + 0x7fffu + ((a.u >> 16) & 1u);
  return (short)(r >> 16);
}
__device__ __forceinline__ float bf2f(short s) {
  union { uint32_t u; float f; } a; a.u = ((uint32_t)(uint16_t)s) << 16;
  return a.f;
}
__device__ __forceinline__ uint32_t pack2bf(float a, float b) {  // trunc pack
  union { float f; uint32_t u; } x, y; x.f = a; y.f = b;
  return (x.u >> 16) | (y.u & 0xffff0000u);
}
__device__ __forceinline__ float fast_exp2(float x) {
#if __has_builtin(__builtin_amdgcn_exp2f)
  return __builtin_amdgcn_exp2f(x);
#else
  return exp2f(x);
#endif
}
__device__ __forceinline__ void async16(const void* g, void* l) {
  __builtin_amdgcn_global_load_lds(
      (const __attribute__((address_space(1))) uint32_t*)g,
      (__attribute__((address_space(3))) uint32_t*)l, 16, 0, 0);
}
#define MFMA(a, b, c) __builtin_amdgcn_mfma_f32_16x16x32_bf16((a), (b), (c), 0, 0, 0)

// ---------------------------------------------------------------------------
// 1) split x (fp32) -> xhi, xlo bf16
// ---------------------------------------------------------------------------
__global__ void k_split_x(const float* __restrict__ x, short* __restrict__ xhi,
                          short* __restrict__ xlo) {
  int i = blockIdx.x * 256 + threadIdx.x;
  float4 v = ((const float4*)x)[i];
  short4 h, l;
  h.x = f2bf(v.x); l.x = f2bf(v.x - bf2f(h.x));
  h.y = f2bf(v.y); l.y = f2bf(v.y - bf2f(h.y));
  h.z = f2bf(v.z); l.z = f2bf(v.z - bf2f(h.z));
  h.w = f2bf(v.w); l.w = f2bf(v.w - bf2f(h.w));
  ((short4*)xhi)[i] = h;
  ((short4*)xlo)[i] = l;
}

// ---------------------------------------------------------------------------
// 2) W[k][n] fp32 -> Wt[n][k] bf16. q,k,v -> whi[z*1M]; o -> wo (separate).
// ---------------------------------------------------------------------------
__global__ void k_prep_w(const float* __restrict__ Wq, const float* __restrict__ Wk,
                         const float* __restrict__ Wv, const float* __restrict__ Wo,
                         short* __restrict__ whi, short* __restrict__ wo) {
  __shared__ float T[64][65];
  int z = blockIdx.z;
  const float* W = (z == 0) ? Wq : (z == 1) ? Wk : (z == 2) ? Wv : Wo;
  int n0 = blockIdx.x * 64, k0 = blockIdx.y * 64;
  int t = threadIdx.x;
  int rr = t >> 4, cc = (t & 15) * 4;
#pragma unroll
  for (int it = 0; it < 4; ++it) {
    int row = rr + it * 16;
    float4 v = *(const float4*)&W[(size_t)(k0 + row) * 1024 + n0 + cc];
    T[row][cc] = v.x; T[row][cc + 1] = v.y; T[row][cc + 2] = v.z; T[row][cc + 3] = v.w;
  }
  __syncthreads();
  short* oh = (z < 3) ? (whi + (size_t)z * 1048576) : wo;
#pragma unroll
  for (int it = 0; it < 4; ++it) {
    int nrow = rr + it * 16;
    short4 h4;
    h4.x = f2bf(T[cc + 0][nrow]);
    h4.y = f2bf(T[cc + 1][nrow]);
    h4.z = f2bf(T[cc + 2][nrow]);
    h4.w = f2bf(T[cc + 3][nrow]);
    *(short4*)&oh[(size_t)(n0 + nrow) * 1024 + k0 + cc] = h4;
  }
}

// ---------------------------------------------------------------------------
// 3) fused QKV projection GEMM (dbuf, single barrier/k-step).
//    Q-proj scaled by LOG2E. V blocks write Vt TRANSPOSED directly.
// ---------------------------------------------------------------------------
__global__ __launch_bounds__(256, 3) void k_gemm_qkv(
    const short* __restrict__ xhi, const short* __restrict__ xlo,
    const short* __restrict__ whi,
    const float* __restrict__ bq, const float* __restrict__ bk,
    const float* __restrict__ bv,
    short* __restrict__ Qhi, short* __restrict__ Qlo,
    short* __restrict__ Khi, short* __restrict__ Klo,
    short* __restrict__ Vt) {
  __shared__ short AH[2][4096];
  __shared__ short AL[2][4096];
  __shared__ short BH[2][4096];
  int tid = threadIdx.x;
  int bx = blockIdx.x;                 // 0..23 ; z = bx>>3 : 0=Q 1=K 2=V
  int m0 = blockIdx.y * 128;
  int n0g = bx * 128;
  bool SPLIT = (bx < 16);
  int w = tid >> 6, lane = tid & 63, lr = lane & 15, lq = lane >> 4;
  int wm = w >> 1, wn = w & 1;
  f32x4 acc[4][4] = {};

  auto stage = [&](int ks, int pb) {
#pragma unroll
    for (int it = 0; it < 2; ++it) {
      int idx = it * 256 + tid;
      int row = idx >> 2, c = idx & 3;
      int cs = c ^ (row & 3);
      size_t ga = (size_t)(m0 + row) * 1024 + ks * 32 + cs * 8;
      async16(xhi + ga, &AH[pb][idx * 8]);
      if (SPLIT) async16(xlo + ga, &AL[pb][idx * 8]);
      size_t gb = (size_t)(n0g + row) * 1024 + ks * 32 + cs * 8;
      async16(whi + gb, &BH[pb][idx * 8]);
    }
  };

  stage(0, 0);
  int p = 0;
  int g = lq ^ (lr & 3);
  for (int ks = 0; ks < 32; ++ks) {
    __syncthreads();
    if (ks < 31) stage(ks + 1, p ^ 1);
    const bf16x8* A8 = (const bf16x8*)AH[p];
    const bf16x8* L8 = (const bf16x8*)AL[p];
    const bf16x8* B8 = (const bf16x8*)BH[p];
    bf16x8 af[4], al[4], bfr[4];
#pragma unroll
    for (int mt = 0; mt < 4; ++mt) af[mt] = A8[(wm * 64 + mt * 16 + lr) * 4 + g];
#pragma unroll
    for (int nt = 0; nt < 4; ++nt) bfr[nt] = B8[(wn * 64 + nt * 16 + lr) * 4 + g];
    if (SPLIT) {
#pragma unroll
      for (int mt = 0; mt < 4; ++mt) al[mt] = L8[(wm * 64 + mt * 16 + lr) * 4 + g];
    }
#pragma unroll
    for (int mt = 0; mt < 4; ++mt)
#pragma unroll
      for (int nt = 0; nt < 4; ++nt)
        acc[mt][nt] = MFMA(af[mt], bfr[nt], acc[mt][nt]);
    if (SPLIT) {
#pragma unroll
      for (int mt = 0; mt < 4; ++mt)
#pragma unroll
        for (int nt = 0; nt < 4; ++nt)
          acc[mt][nt] = MFMA(al[mt], bfr[nt], acc[mt][nt]);
    }
    p ^= 1;
  }

  int z = bx >> 3;
  const float LOG2E = 1.44269504f;
  if (z == 2) {
    // V: write transposed Vt[(b*16+h)*64+dk][s], bias fused, short4 packs
#pragma unroll
    for (int nt = 0; nt < 4; ++nt) {
      int dg = (n0g & 1023) + wn * 64 + nt * 16 + lr;
      float bvv = bv[dg];
      int hh = dg >> 6, dk = dg & 63;
#pragma unroll
      for (int mt = 0; mt < 4; ++mt) {
        int row = m0 + wm * 64 + mt * 16 + lq * 4;
        int b_ = row >> 11, s_ = row & 2047;
        short4 pk;
        pk.x = f2bf(acc[mt][nt][0] + bvv);
        pk.y = f2bf(acc[mt][nt][1] + bvv);
        pk.z = f2bf(acc[mt][nt][2] + bvv);
        pk.w = f2bf(acc[mt][nt][3] + bvv);
        *(short4*)&Vt[(size_t)((b_ * 16 + hh) * 64 + dk) * 2048 + s_] = pk;
      }
    }
  } else {
    const float* bias = (z == 0) ? bq : bk;
    short* Ch = (z == 0) ? Qhi : Khi;
    short* Cl = (z == 0) ? Qlo : Klo;
#pragma unroll
    for (int nt = 0; nt < 4; ++nt) {
      int colg = (n0g & 1023) + wn * 64 + nt * 16 + lr;
      float bvv = bias[colg];
#pragma unroll
      for (int mt = 0; mt < 4; ++mt)
#pragma unroll
        for (int r = 0; r < 4; ++r) {
          int row = m0 + wm * 64 + mt * 16 + lq * 4 + r;
          float v = acc[mt][nt][r] + bvv;
          if (z == 0) v *= LOG2E;       // base-2 softmax folding
          size_t o = (size_t)row * 1024 + colg;
          short hh = f2bf(v);
          Ch[o] = hh;
          Cl[o] = f2bf(v - bf2f(hh));
        }
    }
  }
}

// ---------------------------------------------------------------------------
// 4) O-projection GEMM: out = Obuf @ Wo^T + bo, fp32 out.
//    128x64 tiles -> 512 blocks = 2/CU. Wave w covers rows w*32..w*32+31.
// ---------------------------------------------------------------------------
__global__ __launch_bounds__(256, 4) void k_gemm_o(
    const short* __restrict__ Ab, const short* __restrict__ Bb,
    const float* __restrict__ bias, float* __restrict__ Cf) {
  __shared__ short AH[2][4096];     // 128 x 32
  __shared__ short BH[2][2048];     // 64 x 32
  int tid = threadIdx.x;
  int m0 = blockIdx.y * 128, n0 = blockIdx.x * 64;
  int w = tid >> 6, lane = tid & 63, lr = lane & 15, lq = lane >> 4;
  f32x4 acc[2][4] = {};

  auto stage = [&](int ks, int pb) {
#pragma unroll
    for (int it = 0; it < 2; ++it) {
      int idx = it * 256 + tid;
      int row = idx >> 2, c = idx & 3;
      int cs = c ^ (row & 3);
      async16(Ab + (size_t)(m0 + row) * 1024 + ks * 32 + cs * 8, &AH[pb][idx * 8]);
    }
    {
      int idx = tid;                 // 256 chunks for 64x32 B tile
      int row = idx >> 2, c = idx & 3;
      int cs = c ^ (row & 3);
      async16(Bb + (size_t)(n0 + row) * 1024 + ks * 32 + cs * 8, &BH[pb][idx * 8]);
    }
  };

  stage(0, 0);
  int p = 0;
  int g = lq ^ (lr & 3);
  for (int ks = 0; ks < 32; ++ks) {
    __syncthreads();
    if (ks < 31) stage(ks + 1, p ^ 1);
    const bf16x8* A8 = (const bf16x8*)AH[p];
    const bf16x8* B8 = (const bf16x8*)BH[p];
    bf16x8 af[2], bfr[4];
#pragma unroll
    for (int mt = 0; mt < 2; ++mt) af[mt] = A8[(w * 32 + mt * 16 + lr) * 4 + g];
#pragma unroll
    for (int nt = 0; nt < 4; ++nt) bfr[nt] = B8[(nt * 16 + lr) * 4 + g];
#pragma unroll
    for (int mt = 0; mt < 2; ++mt)
#pragma unroll
      for (int nt = 0; nt < 4; ++nt)
        acc[mt][nt] = MFMA(af[mt], bfr[nt], acc[mt][nt]);
    p ^= 1;
  }
#pragma unroll
  for (int nt = 0; nt < 4; ++nt) {
    int col = n0 + nt * 16 + lr;
    float bvv = bias[col];
#pragma unroll
    for (int mt = 0; mt < 2; ++mt)
#pragma unroll
      for (int r = 0; r < 4; ++r) {
        int row = m0 + w * 32 + mt * 16 + lq * 4 + r;
        Cf[(size_t)row * 1024 + col] = acc[mt][nt][r] + bvv;
      }
  }
}

// ---------------------------------------------------------------------------
// 5) flash attention. Block = equal-trip 4 waves: waves 0,1 -> band 2L-2,
//    waves 2,3 -> band 2L-1 (both need tiles 0..L-1; diagonal in tile L-1).
//    bid: xcd = bid&7, idx = bid>>3; bh = xcd*4 + (idx>>5); L = 32-(idx&31)
//    (longest-first per XCD lane). Dbuf LDS (48KB, 3 blocks/CU), single
//    barrier/iter. S^T QK (3-term split), bpermute P->A-frag, PV,
//    in-kernel normalize.
// ---------------------------------------------------------------------------
__global__ __launch_bounds__(256, 3) void k_attn(
    const short* __restrict__ Khi, const short* __restrict__ Klo,
    const short* __restrict__ Qhi, const short* __restrict__ Qlo,
    const short* __restrict__ Vt, const int* __restrict__ amask,
    short* __restrict__ Obuf) {
  __shared__ short QH[2][4096];     // keys-role hi: [j 64][d 64] swizzled
  __shared__ short QL[2][4096];
  __shared__ short VS[2][4096];     // V^T tile: [d 64][j 64] swizzled
  int tid = threadIdx.x;
  int bid = blockIdx.x;             // 0..1023
  int xcd = bid & 7, idx = bid >> 3;
  int bh = xcd * 4 + (idx >> 5);    // 4 heads per XCD for L2 locality
  int L  = 32 - (idx & 31);         // trip count, descending in idx
  int b = bh >> 4, h = bh & 15;
  int w = tid >> 6, lane = tid & 63, lr = lane & 15, lq = lane >> 4;
  int band = 2 * (L - 1) + (w >> 1);
  int rb0 = band * 32 + (w & 1) * 16;   // wave's 16-row chunk base (in s)

  // keys-role B-fragments (K-proj rows of this wave's chunk), hi+lo
  bf16x8 kh[2], kl[2];
  {
    size_t ra = ((size_t)(b * 2048 + rb0 + lr)) * 1024 + h * 64;
#pragma unroll
    for (int ks = 0; ks < 2; ++ks) {
      kh[ks] = *(const bf16x8*)(Khi + ra + ks * 32 + lq * 8);
      kl[ks] = *(const bf16x8*)(Klo + ra + ks * 32 + lq * 8);
    }
  }

  f32x4 O[4] = {};
  float ls = 0.f;
  int iq = rb0 + lr;                // this lane's query row (s index)
  int baddr0 = (((lq & 1) * 2) * 16 + lr) * 4;   // bpermute byte addrs
  int baddr1 = baddr0 + 64;

  auto stage = [&](int jt, int pb) {
    int j0 = jt * 64;
#pragma unroll
    for (int it = 0; it < 2; ++it) {
      int idx2 = it * 256 + tid;    // 0..511
      int rr = idx2 >> 3, c = idx2 & 7;
      int cs = c ^ (rr & 7);
      size_t gq = ((size_t)(b * 2048 + j0 + rr)) * 1024 + h * 64 + cs * 8;
      async16(Qhi + gq, &QH[pb][idx2 * 8]);
      async16(Qlo + gq, &QL[pb][idx2 * 8]);
      size_t gv = ((size_t)(bh * 64 + rr)) * 2048 + j0 + cs * 8;
      async16(Vt + gv, &VS[pb][idx2 * 8]);
    }
  };

  stage(0, 0);
  int p = 0;
  for (int t = 0; t < L; ++t) {
    __syncthreads();                // buf p staged; buf p^1 free
    if (t + 1 < L) stage(t + 1, p ^ 1);
    int j0 = t * 64;
    const bf16x8* Q8 = (const bf16x8*)QH[p];
    const bf16x8* L8 = (const bf16x8*)QL[p];
    const bf16x8* V8 = (const bf16x8*)VS[p];

    // padding-mask fast path (wave-level)
    int av = amask[b * 2048 + j0 + lane];
    unsigned long long bal = __ballot(av != 0);
    bool allv = (bal == ~0ull);

    // ---- S^T: rows j (4 mt), cols q (lr). 3-term split. ----
    f32x4 s[4] = {};
#pragma unroll
    for (int mt = 0; mt < 4; ++mt) {
      int row = mt * 16 + lr;
#pragma unroll
      for (int ks = 0; ks < 2; ++ks) {
        int gi = row * 8 + ((ks * 4 + lq) ^ (row & 7));
        bf16x8 qa = Q8[gi];
        bf16x8 la = L8[gi];
        s[mt] = MFMA(qa, kh[ks], s[mt]);
        s[mt] = MFMA(la, kh[ks], s[mt]);
        s[mt] = MFMA(qa, kl[ks], s[mt]);
      }
    }

    // ---- exp2 / masks / rowsum / pack ----
    bool diag = (t == L - 1);
    float pv[4][4];
#pragma unroll
    for (int mt = 0; mt < 4; ++mt)
#pragma unroll
      for (int r = 0; r < 4; ++r)
        pv[mt][r] = fast_exp2(s[mt][r]);
    if (diag) {
#pragma unroll
      for (int mt = 0; mt < 4; ++mt)
#pragma unroll
        for (int r = 0; r < 4; ++r)
          if (j0 + mt * 16 + lq * 4 + r > iq) pv[mt][r] = 0.f;
    }
    if (!allv) {
#pragma unroll
      for (int mt = 0; mt < 4; ++mt)
#pragma unroll
        for (int r = 0; r < 4; ++r)
          if (!((bal >> (mt * 16 + lq * 4 + r)) & 1)) pv[mt][r] = 0.f;
    }
    uint32_t pd[4][2];
#pragma unroll
    for (int mt = 0; mt < 4; ++mt) {
      ls += (pv[mt][0] + pv[mt][1]) + (pv[mt][2] + pv[mt][3]);
      pd[mt][0] = pack2bf(pv[mt][0], pv[mt][1]);
      pd[mt][1] = pack2bf(pv[mt][2], pv[mt][3]);
    }

    // ---- P^T -> A-frag via bpermute; PV ----
#pragma unroll
    for (int k2 = 0; k2 < 2; ++k2) {
      union { int i[4]; bf16x8 v; } pa;
#pragma unroll
      for (int dd = 0; dd < 4; ++dd) {
        int addr = (dd >> 1) ? baddr1 : baddr0;
        int v0 = __builtin_amdgcn_ds_bpermute(addr, (int)pd[k2 * 2 + 0][dd & 1]);
        int v1 = __builtin_amdgcn_ds_bpermute(addr, (int)pd[k2 * 2 + 1][dd & 1]);
        pa.i[dd] = (lq >> 1) ? v1 : v0;
      }
#pragma unroll
      for (int nt = 0; nt < 4; ++nt) {
        int row = nt * 16 + lr;
        bf16x8 vb = V8[row * 8 + ((k2 * 4 + lq) ^ (row & 7))];
        O[nt] = MFMA(pa.v, vb, O[nt]);
      }
    }
    p ^= 1;
  }

  // ---- epilogue: reduce rowsum over lq, normalize, store ----
  float tsum = ls;
  tsum += __shfl_xor(tsum, 16);
  tsum += __shfl_xor(tsum, 32);
  float inv[4];
#pragma unroll
  for (int r = 0; r < 4; ++r) inv[r] = 1.0f / __shfl(tsum, lq * 4 + r, 64);
#pragma unroll
  for (int nt = 0; nt < 4; ++nt)
#pragma unroll
    for (int r = 0; r < 4; ++r) {
      int row = b * 2048 + rb0 + lq * 4 + r;
      int col = h * 64 + nt * 16 + lr;
      Obuf[(size_t)row * 1024 + col] = f2bf(O[nt][r] * inv[r]);
    }
}

// ---------------------------------------------------------------------------
// launcher
// ---------------------------------------------------------------------------
extern "C" void kernel_launch(void* const* d_in, const int* in_sizes, int n_in,
                              void* d_out, int out_size, void* d_ws, size_t ws_size,
                              hipStream_t stream) {
  const float* x  = (const float*)d_in[0];
  const int* amask = (const int*)d_in[1];
  const float* Wq = (const float*)d_in[2];
  const float* bq = (const float*)d_in[3];
  const float* Wk = (const float*)d_in[4];
  const float* bk = (const float*)d_in[5];
  const float* Wv = (const float*)d_in[6];
  const float* bv = (const float*)d_in[7];
  const float* Wo = (const float*)d_in[8];
  const float* bo = (const float*)d_in[9];

  char* ws = (char*)d_ws;
  const size_t MB = 1024 * 1024;
  short* xhi = (short*)(ws);             // 0..8MB; dead after qkv -> Obuf
  short* xlo = (short*)(ws + 8 * MB);    // 8..16
  short* whi = (short*)(ws + 16 * MB);   // 16..22 (q,k,v)
  short* wo  = (short*)(ws + 26 * MB);   // 26..28
  short* Qhi = (short*)(ws + 28 * MB);
  short* Qlo = (short*)(ws + 36 * MB);
  short* Khi = (short*)(ws + 44 * MB);
  short* Klo = (short*)(ws + 52 * MB);
  short* Vt  = (short*)(ws + 60 * MB);   // total 68MB
  short* Obuf = xhi;                     // xhi dead after qkv

  k_split_x<<<4096, 256, 0, stream>>>(x, xhi, xlo);
  k_prep_w<<<dim3(16, 16, 4), 256, 0, stream>>>(Wq, Wk, Wv, Wo, whi, wo);

  k_gemm_qkv<<<dim3(24, 32), 256, 0, stream>>>(xhi, xlo, whi, bq, bk, bv,
                                               Qhi, Qlo, Khi, Klo, Vt);
  k_attn<<<1024, 256, 0, stream>>>(Khi, Klo, Qhi, Qlo, Vt, amask, Obuf);
  k_gemm_o<<<dim3(16, 32), 256, 0, stream>>>(Obuf, wo, bo, (float*)d_out);
}

// Round 9
// 210.878 us; speedup vs baseline: 1.4137x; 1.1351x over previous
//
#include <hip/hip_runtime.h>
#include <stdint.h>
#include <stddef.h>

// ---------------------------------------------------------------------------
// MaskedMultiHeadAttn: B=2, S=2048, D=1024, H=16, DK=64, fp32 in/out.
// scores = K·Q^T (roles swapped), NO 1/sqrt(dk) scale, causal+pad mask.
// R9: GEMM-stack round — (1) x-lo term dropped from QKV projection (plain
//     16-MFMA k-loop; epilogue still splits fp32 acc into Q/K hi+lo, so the
//     attention 3-term QK^T is unchanged); (2) k_gemm_o re-tiled 64x64
//     (1024 blocks = 4/CU); (3) k_attn global LPT dispatch order.
// ---------------------------------------------------------------------------

typedef short bf16x8 __attribute__((ext_vector_type(8)));  // 8 bf16 = 4 VGPR
typedef float f32x4  __attribute__((ext_vector_type(4)));

__device__ __forceinline__ short f2bf(float f) {          // RNE
  union { float f; uint32_t u; } a; a.f = f;
  uint32_t r = a.u + 0x7fffu + ((a.u >> 16) & 1u);
  return (short)(r >> 16);
}
__device__ __forceinline__ float bf2f(short s) {
  union { uint32_t u; float f; } a; a.u = ((uint32_t)(uint16_t)s) << 16;
  return a.f;
}
__device__ __forceinline__ uint32_t pack2bf(float a, float b) {  // trunc pack
  union { float f; uint32_t u; } x, y; x.f = a; y.f = b;
  return (x.u >> 16) | (y.u & 0xffff0000u);
}
__device__ __forceinline__ float fast_exp2(float x) {
#if __has_builtin(__builtin_amdgcn_exp2f)
  return __builtin_amdgcn_exp2f(x);
#else
  return exp2f(x);
#endif
}
__device__ __forceinline__ void async16(const void* g, void* l) {
  __builtin_amdgcn_global_load_lds(
      (const __attribute__((address_space(1))) uint32_t*)g,
      (__attribute__((address_space(3))) uint32_t*)l, 16, 0, 0);
}
#define MFMA(a, b, c) __builtin_amdgcn_mfma_f32_16x16x32_bf16((a), (b), (c), 0, 0, 0)

// ---------------------------------------------------------------------------
// 1) cast x (fp32) -> xhi bf16 (x-lo dropped in R9)
// ---------------------------------------------------------------------------
__global__ void k_split_x(const float* __restrict__ x, short* __restrict__ xhi) {
  int i = blockIdx.x * 256 + threadIdx.x;
  float4 v = ((const float4*)x)[i];
  short4 h;
  h.x = f2bf(v.x);
  h.y = f2bf(v.y);
  h.z = f2bf(v.z);
  h.w = f2bf(v.w);
  ((short4*)xhi)[i] = h;
}

// ---------------------------------------------------------------------------
// 2) W[k][n] fp32 -> Wt[n][k] bf16. q,k,v -> whi[z*1M]; o -> wo (separate).
// ---------------------------------------------------------------------------
__global__ void k_prep_w(const float* __restrict__ Wq, const float* __restrict__ Wk,
                         const float* __restrict__ Wv, const float* __restrict__ Wo,
                         short* __restrict__ whi, short* __restrict__ wo) {
  __shared__ float T[64][65];
  int z = blockIdx.z;
  const float* W = (z == 0) ? Wq : (z == 1) ? Wk : (z == 2) ? Wv : Wo;
  int n0 = blockIdx.x * 64, k0 = blockIdx.y * 64;
  int t = threadIdx.x;
  int rr = t >> 4, cc = (t & 15) * 4;
#pragma unroll
  for (int it = 0; it < 4; ++it) {
    int row = rr + it * 16;
    float4 v = *(const float4*)&W[(size_t)(k0 + row) * 1024 + n0 + cc];
    T[row][cc] = v.x; T[row][cc + 1] = v.y; T[row][cc + 2] = v.z; T[row][cc + 3] = v.w;
  }
  __syncthreads();
  short* oh = (z < 3) ? (whi + (size_t)z * 1048576) : wo;
#pragma unroll
  for (int it = 0; it < 4; ++it) {
    int nrow = rr + it * 16;
    short4 h4;
    h4.x = f2bf(T[cc + 0][nrow]);
    h4.y = f2bf(T[cc + 1][nrow]);
    h4.z = f2bf(T[cc + 2][nrow]);
    h4.w = f2bf(T[cc + 3][nrow]);
    *(short4*)&oh[(size_t)(n0 + nrow) * 1024 + k0 + cc] = h4;
  }
}

// ---------------------------------------------------------------------------
// 3) fused QKV projection GEMM (plain bf16, dbuf, single barrier/k-step).
//    Q-proj scaled by LOG2E. Q/K epilogues split fp32 acc -> hi/lo bf16.
//    V blocks write Vt TRANSPOSED directly.
// ---------------------------------------------------------------------------
__global__ __launch_bounds__(256, 3) void k_gemm_qkv(
    const short* __restrict__ xhi, const short* __restrict__ whi,
    const float* __restrict__ bq, const float* __restrict__ bk,
    const float* __restrict__ bv,
    short* __restrict__ Qhi, short* __restrict__ Qlo,
    short* __restrict__ Khi, short* __restrict__ Klo,
    short* __restrict__ Vt) {
  __shared__ short AH[2][4096];
  __shared__ short BH[2][4096];
  int tid = threadIdx.x;
  int bx = blockIdx.x;                 // 0..23 ; z = bx>>3 : 0=Q 1=K 2=V
  int m0 = blockIdx.y * 128;
  int n0g = bx * 128;
  int w = tid >> 6, lane = tid & 63, lr = lane & 15, lq = lane >> 4;
  int wm = w >> 1, wn = w & 1;
  f32x4 acc[4][4] = {};

  auto stage = [&](int ks, int pb) {
#pragma unroll
    for (int it = 0; it < 2; ++it) {
      int idx = it * 256 + tid;
      int row = idx >> 2, c = idx & 3;
      int cs = c ^ (row & 3);
      async16(xhi + (size_t)(m0 + row) * 1024 + ks * 32 + cs * 8, &AH[pb][idx * 8]);
      async16(whi + (size_t)(n0g + row) * 1024 + ks * 32 + cs * 8, &BH[pb][idx * 8]);
    }
  };

  stage(0, 0);
  int p = 0;
  int g = lq ^ (lr & 3);
  for (int ks = 0; ks < 32; ++ks) {
    __syncthreads();
    if (ks < 31) stage(ks + 1, p ^ 1);
    const bf16x8* A8 = (const bf16x8*)AH[p];
    const bf16x8* B8 = (const bf16x8*)BH[p];
    bf16x8 af[4], bfr[4];
#pragma unroll
    for (int mt = 0; mt < 4; ++mt) af[mt] = A8[(wm * 64 + mt * 16 + lr) * 4 + g];
#pragma unroll
    for (int nt = 0; nt < 4; ++nt) bfr[nt] = B8[(wn * 64 + nt * 16 + lr) * 4 + g];
#pragma unroll
    for (int mt = 0; mt < 4; ++mt)
#pragma unroll
      for (int nt = 0; nt < 4; ++nt)
        acc[mt][nt] = MFMA(af[mt], bfr[nt], acc[mt][nt]);
    p ^= 1;
  }

  int z = bx >> 3;
  const float LOG2E = 1.44269504f;
  if (z == 2) {
    // V: write transposed Vt[(b*16+h)*64+dk][s], bias fused, short4 packs
#pragma unroll
    for (int nt = 0; nt < 4; ++nt) {
      int dg = (n0g & 1023) + wn * 64 + nt * 16 + lr;
      float bvv = bv[dg];
      int hh = dg >> 6, dk = dg & 63;
#pragma unroll
      for (int mt = 0; mt < 4; ++mt) {
        int row = m0 + wm * 64 + mt * 16 + lq * 4;
        int b_ = row >> 11, s_ = row & 2047;
        short4 pk;
        pk.x = f2bf(acc[mt][nt][0] + bvv);
        pk.y = f2bf(acc[mt][nt][1] + bvv);
        pk.z = f2bf(acc[mt][nt][2] + bvv);
        pk.w = f2bf(acc[mt][nt][3] + bvv);
        *(short4*)&Vt[(size_t)((b_ * 16 + hh) * 64 + dk) * 2048 + s_] = pk;
      }
    }
  } else {
    const float* bias = (z == 0) ? bq : bk;
    short* Ch = (z == 0) ? Qhi : Khi;
    short* Cl = (z == 0) ? Qlo : Klo;
#pragma unroll
    for (int nt = 0; nt < 4; ++nt) {
      int colg = (n0g & 1023) + wn * 64 + nt * 16 + lr;
      float bvv = bias[colg];
#pragma unroll
      for (int mt = 0; mt < 4; ++mt)
#pragma unroll
        for (int r = 0; r < 4; ++r) {
          int row = m0 + wm * 64 + mt * 16 + lq * 4 + r;
          float v = acc[mt][nt][r] + bvv;
          if (z == 0) v *= LOG2E;       // base-2 softmax folding
          size_t o = (size_t)row * 1024 + colg;
          short hh = f2bf(v);
          Ch[o] = hh;
          Cl[o] = f2bf(v - bf2f(hh));   // fp32-accurate split outputs
        }
    }
  }
}

// ---------------------------------------------------------------------------
// 4) O-projection GEMM: out = Obuf @ Wo^T + bo, fp32 out.
//    64x64 tiles -> grid (16,64) = 1024 blocks = 4/CU, 16KB LDS.
//    Wave w computes rows w*16..w*16+15 x 64 cols.
// ---------------------------------------------------------------------------
__global__ __launch_bounds__(256, 4) void k_gemm_o(
    const short* __restrict__ Ab, const short* __restrict__ Bb,
    const float* __restrict__ bias, float* __restrict__ Cf) {
  __shared__ short AH[2][2048];     // 64 x 32
  __shared__ short BH[2][2048];     // 64 x 32
  int tid = threadIdx.x;
  int m0 = blockIdx.y * 64, n0 = blockIdx.x * 64;
  int w = tid >> 6, lane = tid & 63, lr = lane & 15, lq = lane >> 4;
  f32x4 acc[4] = {};

  auto stage = [&](int ks, int pb) {
    int row = tid >> 2, c = tid & 3;
    int cs = c ^ (row & 3);
    async16(Ab + (size_t)(m0 + row) * 1024 + ks * 32 + cs * 8, &AH[pb][tid * 8]);
    async16(Bb + (size_t)(n0 + row) * 1024 + ks * 32 + cs * 8, &BH[pb][tid * 8]);
  };

  stage(0, 0);
  int p = 0;
  int g = lq ^ (lr & 3);
  for (int ks = 0; ks < 32; ++ks) {
    __syncthreads();
    if (ks < 31) stage(ks + 1, p ^ 1);
    const bf16x8* A8 = (const bf16x8*)AH[p];
    const bf16x8* B8 = (const bf16x8*)BH[p];
    bf16x8 af = A8[(w * 16 + lr) * 4 + g];
    bf16x8 bfr[4];
#pragma unroll
    for (int nt = 0; nt < 4; ++nt) bfr[nt] = B8[(nt * 16 + lr) * 4 + g];
#pragma unroll
    for (int nt = 0; nt < 4; ++nt)
      acc[nt] = MFMA(af, bfr[nt], acc[nt]);
    p ^= 1;
  }
#pragma unroll
  for (int nt = 0; nt < 4; ++nt) {
    int col = n0 + nt * 16 + lr;
    float bvv = bias[col];
#pragma unroll
    for (int r = 0; r < 4; ++r) {
      int row = m0 + w * 16 + lq * 4 + r;
      Cf[(size_t)row * 1024 + col] = acc[nt][r] + bvv;
    }
  }
}

// ---------------------------------------------------------------------------
// 5) flash attention. Block = equal-trip 4 waves: waves 0,1 -> band 2L-2,
//    waves 2,3 -> band 2L-1 (both need tiles 0..L-1; diagonal in tile L-1).
//    Global LPT order: L = 32-(idx>>2) (all longest blocks dispatch first),
//    bh = xcd*4 + (idx&3) keeps 4 heads per XCD (L2 locality). Dbuf LDS
//    (48KB, 3 blocks/CU), single barrier/iter. S^T QK (3-term split),
//    bpermute P->A-frag, PV, in-kernel normalize.
// ---------------------------------------------------------------------------
__global__ __launch_bounds__(256, 3) void k_attn(
    const short* __restrict__ Khi, const short* __restrict__ Klo,
    const short* __restrict__ Qhi, const short* __restrict__ Qlo,
    const short* __restrict__ Vt, const int* __restrict__ amask,
    short* __restrict__ Obuf) {
  __shared__ short QH[2][4096];     // keys-role hi: [j 64][d 64] swizzled
  __shared__ short QL[2][4096];
  __shared__ short VS[2][4096];     // V^T tile: [d 64][j 64] swizzled
  int tid = threadIdx.x;
  int bid = blockIdx.x;             // 0..1023
  int xcd = bid & 7, idx = bid >> 3;
  int bh = xcd * 4 + (idx & 3);     // 4 heads per XCD for L2 locality
  int L  = 32 - (idx >> 2);         // trip count, global LPT (longest first)
  int b = bh >> 4, h = bh & 15;
  int w = tid >> 6, lane = tid & 63, lr = lane & 15, lq = lane >> 4;
  int band = 2 * (L - 1) + (w >> 1);
  int rb0 = band * 32 + (w & 1) * 16;   // wave's 16-row chunk base (in s)

  // keys-role B-fragments (K-proj rows of this wave's chunk), hi+lo
  bf16x8 kh[2], kl[2];
  {
    size_t ra = ((size_t)(b * 2048 + rb0 + lr)) * 1024 + h * 64;
#pragma unroll
    for (int ks = 0; ks < 2; ++ks) {
      kh[ks] = *(const bf16x8*)(Khi + ra + ks * 32 + lq * 8);
      kl[ks] = *(const bf16x8*)(Klo + ra + ks * 32 + lq * 8);
    }
  }

  f32x4 O[4] = {};
  float ls = 0.f;
  int iq = rb0 + lr;                // this lane's query row (s index)
  int baddr0 = (((lq & 1) * 2) * 16 + lr) * 4;   // bpermute byte addrs
  int baddr1 = baddr0 + 64;

  auto stage = [&](int jt, int pb) {
    int j0 = jt * 64;
#pragma unroll
    for (int it = 0; it < 2; ++it) {
      int idx2 = it * 256 + tid;    // 0..511
      int rr = idx2 >> 3, c = idx2 & 7;
      int cs = c ^ (rr & 7);
      size_t gq = ((size_t)(b * 2048 + j0 + rr)) * 1024 + h * 64 + cs * 8;
      async16(Qhi + gq, &QH[pb][idx2 * 8]);
      async16(Qlo + gq, &QL[pb][idx2 * 8]);
      size_t gv = ((size_t)(bh * 64 + rr)) * 2048 + j0 + cs * 8;
      async16(Vt + gv, &VS[pb][idx2 * 8]);
    }
  };

  stage(0, 0);
  int p = 0;
  for (int t = 0; t < L; ++t) {
    __syncthreads();                // buf p staged; buf p^1 free
    if (t + 1 < L) stage(t + 1, p ^ 1);
    int j0 = t * 64;
    const bf16x8* Q8 = (const bf16x8*)QH[p];
    const bf16x8* L8 = (const bf16x8*)QL[p];
    const bf16x8* V8 = (const bf16x8*)VS[p];

    // padding-mask fast path (wave-level)
    int av = amask[b * 2048 + j0 + lane];
    unsigned long long bal = __ballot(av != 0);
    bool allv = (bal == ~0ull);

    // ---- S^T: rows j (4 mt), cols q (lr). 3-term split. ----
    f32x4 s[4] = {};
#pragma unroll
    for (int mt = 0; mt < 4; ++mt) {
      int row = mt * 16 + lr;
#pragma unroll
      for (int ks = 0; ks < 2; ++ks) {
        int gi = row * 8 + ((ks * 4 + lq) ^ (row & 7));
        bf16x8 qa = Q8[gi];
        bf16x8 la = L8[gi];
        s[mt] = MFMA(qa, kh[ks], s[mt]);
        s[mt] = MFMA(la, kh[ks], s[mt]);
        s[mt] = MFMA(qa, kl[ks], s[mt]);
      }
    }

    // ---- exp2 / masks / rowsum / pack ----
    bool diag = (t == L - 1);
    float pv[4][4];
#pragma unroll
    for (int mt = 0; mt < 4; ++mt)
#pragma unroll
      for (int r = 0; r < 4; ++r)
        pv[mt][r] = fast_exp2(s[mt][r]);
    if (diag) {
#pragma unroll
      for (int mt = 0; mt < 4; ++mt)
#pragma unroll
        for (int r = 0; r < 4; ++r)
          if (j0 + mt * 16 + lq * 4 + r > iq) pv[mt][r] = 0.f;
    }
    if (!allv) {
#pragma unroll
      for (int mt = 0; mt < 4; ++mt)
#pragma unroll
        for (int r = 0; r < 4; ++r)
          if (!((bal >> (mt * 16 + lq * 4 + r)) & 1)) pv[mt][r] = 0.f;
    }
    uint32_t pd[4][2];
#pragma unroll
    for (int mt = 0; mt < 4; ++mt) {
      ls += (pv[mt][0] + pv[mt][1]) + (pv[mt][2] + pv[mt][3]);
      pd[mt][0] = pack2bf(pv[mt][0], pv[mt][1]);
      pd[mt][1] = pack2bf(pv[mt][2], pv[mt][3]);
    }

    // ---- P^T -> A-frag via bpermute; PV ----
#pragma unroll
    for (int k2 = 0; k2 < 2; ++k2) {
      union { int i[4]; bf16x8 v; } pa;
#pragma unroll
      for (int dd = 0; dd < 4; ++dd) {
        int addr = (dd >> 1) ? baddr1 : baddr0;
        int v0 = __builtin_amdgcn_ds_bpermute(addr, (int)pd[k2 * 2 + 0][dd & 1]);
        int v1 = __builtin_amdgcn_ds_bpermute(addr, (int)pd[k2 * 2 + 1][dd & 1]);
        pa.i[dd] = (lq >> 1) ? v1 : v0;
      }
#pragma unroll
      for (int nt = 0; nt < 4; ++nt) {
        int row = nt * 16 + lr;
        bf16x8 vb = V8[row * 8 + ((k2 * 4 + lq) ^ (row & 7))];
        O[nt] = MFMA(pa.v, vb, O[nt]);
      }
    }
    p ^= 1;
  }

  // ---- epilogue: reduce rowsum over lq, normalize, store ----
  float tsum = ls;
  tsum += __shfl_xor(tsum, 16);
  tsum += __shfl_xor(tsum, 32);
  float inv[4];
#pragma unroll
  for (int r = 0; r < 4; ++r) inv[r] = 1.0f / __shfl(tsum, lq * 4 + r, 64);
#pragma unroll
  for (int nt = 0; nt < 4; ++nt)
#pragma unroll
    for (int r = 0; r < 4; ++r) {
      int row = b * 2048 + rb0 + lq * 4 + r;
      int col = h * 64 + nt * 16 + lr;
      Obuf[(size_t)row * 1024 + col] = f2bf(O[nt][r] * inv[r]);
    }
}

// ---------------------------------------------------------------------------
// launcher
// ---------------------------------------------------------------------------
extern "C" void kernel_launch(void* const* d_in, const int* in_sizes, int n_in,
                              void* d_out, int out_size, void* d_ws, size_t ws_size,
                              hipStream_t stream) {
  const float* x  = (const float*)d_in[0];
  const int* amask = (const int*)d_in[1];
  const float* Wq = (const float*)d_in[2];
  const float* bq = (const float*)d_in[3];
  const float* Wk = (const float*)d_in[4];
  const float* bk = (const float*)d_in[5];
  const float* Wv = (const float*)d_in[6];
  const float* bv = (const float*)d_in[7];
  const float* Wo = (const float*)d_in[8];
  const float* bo = (const float*)d_in[9];

  char* ws = (char*)d_ws;
  const size_t MB = 1024 * 1024;
  short* xhi = (short*)(ws);             // 0..8MB; dead after qkv -> Obuf
  short* whi = (short*)(ws + 16 * MB);   // 16..22 (q,k,v)
  short* wo  = (short*)(ws + 26 * MB);   // 26..28
  short* Qhi = (short*)(ws + 28 * MB);
  short* Qlo = (short*)(ws + 36 * MB);
  short* Khi = (short*)(ws + 44 * MB);
  short* Klo = (short*)(ws + 52 * MB);
  short* Vt  = (short*)(ws + 60 * MB);   // total 68MB
  short* Obuf = xhi;                     // xhi dead after qkv

  k_split_x<<<4096, 256, 0, stream>>>(x, xhi);
  k_prep_w<<<dim3(16, 16, 4), 256, 0, stream>>>(Wq, Wk, Wv, Wo, whi, wo);

  k_gemm_qkv<<<dim3(24, 32), 256, 0, stream>>>(xhi, whi, bq, bk, bv,
                                               Qhi, Qlo, Khi, Klo, Vt);
  k_attn<<<1024, 256, 0, stream>>>(Khi, Klo, Qhi, Qlo, Vt, amask, Obuf);
  k_gemm_o<<<dim3(16, 64), 256, 0, stream>>>(Obuf, wo, bo, (float*)d_out);
}